// Round 1
// baseline (1983.019 us; speedup 1.0000x reference)
//
#include <hip/hip_runtime.h>
#include <math.h>

// Problem constants: B=8, Cin=64, Cout=32, H=W=8 (P=64 pixels), RH=32, E=512.
//
// Pipeline:
//  kF: forward conv stack (record relu masks), hopfield(y) -> g = 2(y - yq),
//      precompute X1W[b][i][k][co] = sum_ci x[b,ci,i]*W1[co,ci,k],
//      Wsum[k][co] = sum_ci W1[co,ci,k], and transposed res/conv2 weights.
//  kJ: 1024 waves, one per (b, i, tangent-type). JVP through the mask-
//      linearized network. type==0 (ones tangent): e_m = sum_o g*out -> argmin
//      over lanes -> idx[b,i]. type==1 (x tangent): store T[b][i][o][m].
//  kH: y_masked[b,o,m] = sum_{i: idx=m} T[b,i,o,m]; hopfield -> d_out.

// ---- ws layout (float offsets) ----
constexpr size_t OFF_MASKM = 0;                       // 8*3*4096 = 98304 (M0,M1,M2 per sample)
constexpr size_t OFF_MASKN = OFF_MASKM + 8*3*4096;    // 8*2*2048 = 32768 (N0,N1)
constexpr size_t OFF_G     = OFF_MASKN + 8*2*2048;    // 8*32*64 = 16384
constexpr size_t OFF_X1W   = OFF_G     + 16384;       // 8*64*9*64 = 294912
constexpr size_t OFF_WSUM  = OFF_X1W   + 294912;      // 576 -> pad 640
constexpr size_t OFF_W1RT  = OFF_WSUM  + 640;         // 2*9*64*32 = 36864  [s][k][ci][co]
constexpr size_t OFF_W2RT  = OFF_W1RT  + 36864;       // 2*32*64 = 4096     [s][ci][co]
constexpr size_t OFF_WC2T  = OFF_W2RT  + 4096;        // 64*32 = 2048       [ci][o]
constexpr size_t OFF_T     = OFF_WC2T  + 2048;        // 8*64*32*64 = 1048576 [b][i][o][m]
constexpr size_t OFF_IDX   = OFF_T     + 1048576;     // 512 ints
constexpr size_t WS_FLOATS = OFF_IDX   + 512;         // ~6.1 MB

// Hopfield over one token (pixel). All 64 lanes cooperate: lane handles
// e = k*64+lane for k in [0,8). Returns normalized-numerator q[32] (same in
// all lanes) and 1/denominator.
__device__ __forceinline__ void hopfield_token(const float* __restrict__ pat,
                                               const float* Ys, int tok, int lane,
                                               float q[32], float& inv_d)
{
  const float* patL = pat + lane * 32;
  float l[8];
#pragma unroll
  for (int k = 0; k < 8; k++) l[k] = 0.f;
  for (int c = 0; c < 32; c++) {
    float yv = Ys[c * 64 + tok];
#pragma unroll
    for (int k = 0; k < 8; k++) l[k] = fmaf(yv, patL[k * 2048 + c], l[k]);
  }
  const float s = 0.17677669529663687f; // 1/sqrt(32)
  float mx = -1e30f;
#pragma unroll
  for (int k = 0; k < 8; k++) { l[k] *= s; mx = fmaxf(mx, l[k]); }
#pragma unroll
  for (int off = 32; off > 0; off >>= 1) mx = fmaxf(mx, __shfl_xor(mx, off, 64));
  float num[8]; float dsum = 0.f;
#pragma unroll
  for (int k = 0; k < 8; k++) { num[k] = __expf(l[k] - mx); dsum += num[k]; }
#pragma unroll
  for (int off = 32; off > 0; off >>= 1) dsum += __shfl_xor(dsum, off, 64);
#pragma unroll
  for (int c = 0; c < 32; c++) q[c] = 0.f;
#pragma unroll
  for (int k = 0; k < 8; k++) {
    float nk = num[k];
    const float* pp = patL + k * 2048;
#pragma unroll
    for (int c = 0; c < 32; c++) q[c] = fmaf(nk, pp[c], q[c]);
  }
#pragma unroll
  for (int off = 32; off > 0; off >>= 1) {
#pragma unroll
    for (int c = 0; c < 32; c++) q[c] += __shfl_xor(q[c], off, 64);
  }
  inv_d = 1.f / dsum;
}

__global__ __launch_bounds__(1024) void kF(
    const float* __restrict__ x,  const float* __restrict__ w1, const float* __restrict__ b1,
    const float* __restrict__ r0w1, const float* __restrict__ r0w2,
    const float* __restrict__ r1w1, const float* __restrict__ r1w2,
    const float* __restrict__ w2, const float* __restrict__ b2,
    const float* __restrict__ pat, float* ws)
{
  const int b = blockIdx.x;
  const int t = threadIdx.x;
  const int p = t & 63;        // pixel
  const int g = t >> 6;        // group / wave id (16)
  const int py = p >> 3, px = p & 7;
  __shared__ float Xs[4096], Y[4096], A[4096], Hs[2048];

  for (int e = t; e < 4096; e += 1024) Xs[e] = x[b * 4096 + e];

  if (b == 0) {
    // Wsum[k][co] = sum_ci W1[co,ci,k]
    for (int e = t; e < 576; e += 1024) {
      int k = e >> 6, co = e & 63; float acc = 0.f;
      for (int ci = 0; ci < 64; ci++) acc += w1[(co * 64 + ci) * 9 + k];
      ws[OFF_WSUM + k * 64 + co] = acc;
    }
    // W1rt[s][k][ci][co] = res_w1[co][ci][k]
    for (int e = t; e < 18432; e += 1024) {
      int co = e & 31, ci = (e >> 5) & 63, k = e >> 11;
      ws[OFF_W1RT + e]         = r0w1[(co * 64 + ci) * 9 + k];
      ws[OFF_W1RT + 18432 + e] = r1w1[(co * 64 + ci) * 9 + k];
    }
    // W2rt[s][ci][co] = res_w2[co][ci];  Wc2t[ci][o] = conv2_w[o][ci]
    for (int e = t; e < 2048; e += 1024) {
      int co = e & 63, ci = e >> 6;
      ws[OFF_W2RT + e]        = r0w2[co * 32 + ci];
      ws[OFF_W2RT + 2048 + e] = r1w2[co * 32 + ci];
      int o = e & 31, c2 = e >> 5;
      ws[OFF_WC2T + e] = w2[o * 64 + c2];
    }
  }
  __syncthreads();

  // conv1 3x3 pad1, 64->64 (+bias): this wave's 4 output channels
  {
    const int co0 = g * 4;
    float acc[4];
#pragma unroll
    for (int j = 0; j < 4; j++) acc[j] = b1[co0 + j];
    for (int k = 0; k < 9; k++) {
      int dy = k / 3 - 1, dx = k % 3 - 1;
      int qy = py + dy, qx = px + dx;
      bool vld = (unsigned)qy < 8u && (unsigned)qx < 8u;
      int nb = vld ? qy * 8 + qx : p;
      for (int ci = 0; ci < 64; ci++) {
        float v = Xs[ci * 64 + nb]; v = vld ? v : 0.f;
#pragma unroll
        for (int j = 0; j < 4; j++) acc[j] = fmaf(w1[((co0 + j) * 64 + ci) * 9 + k], v, acc[j]);
      }
    }
#pragma unroll
    for (int j = 0; j < 4; j++) {
      int co = co0 + j;
      Y[co * 64 + p] = acc[j];
      A[co * 64 + p] = fmaxf(acc[j], 0.f);
      ws[OFF_MASKM + (size_t)(b * 3 + 0) * 4096 + co * 64 + p] = acc[j] > 0.f ? 1.f : 0.f;
    }
  }

  // X1W[b][i=p][k][co] = sum_ci x[b,ci,p]*W1[co,ci,k]
  {
    const int co0 = g * 4;
    for (int k = 0; k < 9; k++) {
      float acc[4] = {0.f, 0.f, 0.f, 0.f};
      for (int ci = 0; ci < 64; ci++) {
        float v = Xs[ci * 64 + p];
#pragma unroll
        for (int j = 0; j < 4; j++) acc[j] = fmaf(w1[((co0 + j) * 64 + ci) * 9 + k], v, acc[j]);
      }
#pragma unroll
      for (int j = 0; j < 4; j++)
        ws[OFF_X1W + ((size_t)(b * 64 + p) * 9 + k) * 64 + co0 + j] = acc[j];
    }
  }
  __syncthreads();

  // two residual blocks
  for (int s = 0; s < 2; s++) {
    const float* rw1 = s ? r1w1 : r0w1;
    const float* rw2 = s ? r1w2 : r0w2;
    // conv3x3 A(64) -> Hs(32), record N mask of pre-relu
    {
      const int co0 = g * 2;
      float acc[2] = {0.f, 0.f};
      for (int k = 0; k < 9; k++) {
        int dy = k / 3 - 1, dx = k % 3 - 1;
        int qy = py + dy, qx = px + dx;
        bool vld = (unsigned)qy < 8u && (unsigned)qx < 8u;
        int nb = vld ? qy * 8 + qx : p;
        for (int ci = 0; ci < 64; ci++) {
          float v = A[ci * 64 + nb]; v = vld ? v : 0.f;
          acc[0] = fmaf(rw1[((co0 + 0) * 64 + ci) * 9 + k], v, acc[0]);
          acc[1] = fmaf(rw1[((co0 + 1) * 64 + ci) * 9 + k], v, acc[1]);
        }
      }
#pragma unroll
      for (int j = 0; j < 2; j++) {
        Hs[(co0 + j) * 64 + p] = fmaxf(acc[j], 0.f);
        ws[OFF_MASKN + (size_t)(b * 2 + s) * 2048 + (co0 + j) * 64 + p] = acc[j] > 0.f ? 1.f : 0.f;
      }
    }
    __syncthreads();
    // conv1x1 Hs(32) -> += Y(64); record M mask; A = relu(Y)
    {
      const int co0 = g * 4;
      float acc[4] = {0.f, 0.f, 0.f, 0.f};
      for (int ci = 0; ci < 32; ci++) {
        float v = Hs[ci * 64 + p];
#pragma unroll
        for (int j = 0; j < 4; j++) acc[j] = fmaf(rw2[(co0 + j) * 32 + ci], v, acc[j]);
      }
#pragma unroll
      for (int j = 0; j < 4; j++) {
        int co = co0 + j;
        float ny = Y[co * 64 + p] + acc[j];
        Y[co * 64 + p] = ny;
        A[co * 64 + p] = fmaxf(ny, 0.f);
        ws[OFF_MASKM + (size_t)(b * 3 + 1 + s) * 4096 + co * 64 + p] = ny > 0.f ? 1.f : 0.f;
      }
    }
    __syncthreads();
  }

  // conv2 1x1 A(64) -> y(32) (+bias), into Hs (reused as Ys)
  {
    const int o0 = g * 2;
    float acc[2] = {b2[o0], b2[o0 + 1]};
    for (int ci = 0; ci < 64; ci++) {
      float v = A[ci * 64 + p];
      acc[0] = fmaf(w2[(o0 + 0) * 64 + ci], v, acc[0]);
      acc[1] = fmaf(w2[(o0 + 1) * 64 + ci], v, acc[1]);
    }
    Hs[(o0 + 0) * 64 + p] = acc[0];
    Hs[(o0 + 1) * 64 + p] = acc[1];
  }
  __syncthreads();

  // hopfield(y) -> g = 2*(y - yq)
  for (int tok = g; tok < 64; tok += 16) {
    float q[32]; float invd;
    hopfield_token(pat, Hs, tok, p, q, invd);
    if (p == 0) {
#pragma unroll
      for (int c = 0; c < 32; c++)
        ws[OFF_G + (size_t)b * 2048 + c * 64 + tok] = 2.f * (Hs[c * 64 + tok] - q[c] * invd);
    }
  }
}

__global__ __launch_bounds__(64) void kJ(const float* wsc, float* ws)
{
  const int bid = blockIdx.x;
  const int type = bid & 1;
  const int i    = (bid >> 1) & 63;
  const int b    = bid >> 7;
  const int p = threadIdx.x;
  const int py = p >> 3, px = p & 7, iy = i >> 3, ix = i & 7;
  __shared__ float Tc[4096], U[4096];

  // t0 = conv1 applied to (coef at pixel i): precomputed X1W / Wsum lookup
  {
    int kh = iy - py + 1, kw = ix - px + 1;
    bool v0 = (unsigned)kh < 3u && (unsigned)kw < 3u;
    int kidx = v0 ? kh * 3 + kw : 0;
    const float* src = type ? (wsc + OFF_X1W + ((size_t)(b * 64 + i) * 9 + kidx) * 64)
                            : (wsc + OFF_WSUM + kidx * 64);
    const float4* s4 = (const float4*)src;
    for (int c4 = 0; c4 < 16; c4++) {
      float4 tv = s4[c4];
      Tc[(c4 * 4 + 0) * 64 + p] = v0 ? tv.x : 0.f;
      Tc[(c4 * 4 + 1) * 64 + p] = v0 ? tv.y : 0.f;
      Tc[(c4 * 4 + 2) * 64 + p] = v0 ? tv.z : 0.f;
      Tc[(c4 * 4 + 3) * 64 + p] = v0 ? tv.w : 0.f;
    }
  }

  for (int s = 0; s < 2; s++) {
    // U = M_s * Tc (own column)
    const float* Mp = wsc + OFF_MASKM + (size_t)(b * 3 + s) * 4096;
    for (int ci = 0; ci < 64; ci++)
      U[ci * 64 + p] = Tc[ci * 64 + p] * Mp[ci * 64 + p];
    __syncthreads();
    // conv3x3 U(64) -> v(32)
    float v[32];
#pragma unroll
    for (int c = 0; c < 32; c++) v[c] = 0.f;
    const float* Wt = wsc + OFF_W1RT + (size_t)s * 18432;
    for (int k = 0; k < 9; k++) {
      int dy = k / 3 - 1, dx = k % 3 - 1;
      int qy = py + dy, qx = px + dx;
      bool vld = (unsigned)qy < 8u && (unsigned)qx < 8u;
      int nl = vld ? qy * 8 + qx : p;
      const float4* w4 = (const float4*)(Wt + k * 2048);
      for (int ci = 0; ci < 64; ci++) {
        float sv = U[ci * 64 + nl]; sv = vld ? sv : 0.f;
#pragma unroll
        for (int j = 0; j < 8; j++) {
          float4 w = w4[ci * 8 + j];
          v[j * 4 + 0] = fmaf(w.x, sv, v[j * 4 + 0]);
          v[j * 4 + 1] = fmaf(w.y, sv, v[j * 4 + 1]);
          v[j * 4 + 2] = fmaf(w.z, sv, v[j * 4 + 2]);
          v[j * 4 + 3] = fmaf(w.w, sv, v[j * 4 + 3]);
        }
      }
    }
    // branch mask + conv1x1(32->64) + residual add into Tc (own column)
    const float* Np = wsc + OFF_MASKN + (size_t)(b * 2 + s) * 2048;
    float w0[32];
#pragma unroll
    for (int c = 0; c < 32; c++) w0[c] = v[c] * Np[c * 64 + p];
    __syncthreads();   // all lanes finished reading U before next-stage overwrite
    const float* W2t = wsc + OFF_W2RT + (size_t)s * 2048;
    for (int co = 0; co < 64; co++) {
      float acc = Tc[co * 64 + p];
#pragma unroll
      for (int ci = 0; ci < 32; ci++) acc = fmaf(W2t[ci * 64 + co], w0[ci], acc);
      Tc[co * 64 + p] = acc;
    }
  }

  // final: out = Wc2 . (M2 * t2)   (own column only)
  float out[32];
#pragma unroll
  for (int c = 0; c < 32; c++) out[c] = 0.f;
  {
    const float* M2p = wsc + OFF_MASKM + (size_t)(b * 3 + 2) * 4096;
    const float* Wc  = wsc + OFF_WC2T;
    for (int ci = 0; ci < 64; ci++) {
      float u = Tc[ci * 64 + p] * M2p[ci * 64 + p];
      const float4* w4 = (const float4*)(Wc + ci * 32);
#pragma unroll
      for (int j = 0; j < 8; j++) {
        float4 w = w4[j];
        out[j * 4 + 0] = fmaf(w.x, u, out[j * 4 + 0]);
        out[j * 4 + 1] = fmaf(w.y, u, out[j * 4 + 1]);
        out[j * 4 + 2] = fmaf(w.z, u, out[j * 4 + 2]);
        out[j * 4 + 3] = fmaf(w.w, u, out[j * 4 + 3]);
      }
    }
  }

  if (type == 0) {
    // e_m = sum_o g[b,o,m]*out[o]; argmin over lanes (first index on ties)
    const float* gp = wsc + OFF_G + (size_t)b * 2048;
    float e = 0.f;
#pragma unroll
    for (int o = 0; o < 32; o++) e = fmaf(gp[o * 64 + p], out[o], e);
    float bv = e; int bi = p;
#pragma unroll
    for (int off = 32; off > 0; off >>= 1) {
      float ov = __shfl_xor(bv, off, 64);
      int   oi = __shfl_xor(bi, off, 64);
      if (ov < bv || (ov == bv && oi < bi)) { bv = ov; bi = oi; }
    }
    if (p == 0) ((int*)(ws + OFF_IDX))[b * 64 + i] = bi;
  } else {
    float* Tp = ws + OFF_T + (size_t)(b * 64 + i) * 2048;
#pragma unroll
    for (int o = 0; o < 32; o++) Tp[o * 64 + p] = out[o];
  }
}

__global__ __launch_bounds__(1024) void kH(const float* wsc,
                                           const float* __restrict__ pat,
                                           float* __restrict__ outp)
{
  const int b = blockIdx.x, t = threadIdx.x, p = t & 63, g = t >> 6;
  __shared__ float Ys[2048];
  __shared__ int sidx[64];
  if (t < 64) sidx[t] = ((const int*)(wsc + OFF_IDX))[b * 64 + t];
  __syncthreads();
  for (int o = g; o < 32; o += 16) {
    float acc = 0.f;
    const float* Tp = wsc + OFF_T + (size_t)b * 131072 + o * 64 + p;
    for (int i = 0; i < 64; i++) {
      float tv = Tp[(size_t)i * 2048];
      acc += (sidx[i] == p) ? tv : 0.f;
    }
    Ys[o * 64 + p] = acc;
  }
  __syncthreads();
  for (int tok = g; tok < 64; tok += 16) {
    float q[32]; float invd;
    hopfield_token(pat, Ys, tok, p, q, invd);
    if (p == 0) {
#pragma unroll
      for (int c = 0; c < 32; c++)
        outp[(size_t)b * 2048 + c * 64 + tok] = q[c] * invd;
    }
  }
}

extern "C" void kernel_launch(void* const* d_in, const int* in_sizes, int n_in,
                              void* d_out, int out_size, void* d_ws, size_t ws_size,
                              hipStream_t stream) {
  (void)in_sizes; (void)n_in; (void)out_size; (void)ws_size;
  const float* x    = (const float*)d_in[0];
  const float* w1   = (const float*)d_in[1];
  const float* b1   = (const float*)d_in[2];
  const float* r0w1 = (const float*)d_in[3];
  const float* r0w2 = (const float*)d_in[4];
  const float* r1w1 = (const float*)d_in[5];
  const float* r1w2 = (const float*)d_in[6];
  const float* w2   = (const float*)d_in[7];
  const float* b2   = (const float*)d_in[8];
  const float* pat  = (const float*)d_in[9];
  float* ws  = (float*)d_ws;
  float* out = (float*)d_out;

  kF<<<8, 1024, 0, stream>>>(x, w1, b1, r0w1, r0w2, r1w1, r1w2, w2, b2, pat, ws);
  kJ<<<1024, 64, 0, stream>>>(ws, ws);
  kH<<<8, 1024, 0, stream>>>(ws, pat, out);
}

// Round 2
// 870.448 us; speedup vs baseline: 2.2782x; 2.2782x over previous
//
#include <hip/hip_runtime.h>
#include <math.h>

// B=8, Cin=64, Cout=32, H=W=8 (P=64), RH=32, E=512.
// kW: transpose weights into GEMM-friendly layouts.
// kX: X1W[b][i][k][co] = sum_ci x[b,ci,i] * W1[co,ci,k]   (wide, parallel)
// kF: forward pass per sample (masks, g = 2(y-yq))         (8 blocks x 1024)
// kJ: one wave per (b,i,type): JVP through linearized net  (1024 blocks x 64)
// kH: gather routed T + hopfield -> out                    (8 blocks x 1024)

// ---- ws layout (float offsets) ----
constexpr int OFF_MASKM = 0;                         // 8*3*4096
constexpr int OFF_MASKN = OFF_MASKM + 8*3*4096;      // 8*2*2048
constexpr int OFF_G     = OFF_MASKN + 8*2*2048;      // 8*2048
constexpr int OFF_X1W   = OFF_G     + 16384;         // 8*64*9*64
constexpr int OFF_WSUM  = OFF_X1W   + 294912;        // 576 (pad 640)   [k][co]
constexpr int OFF_W1RT  = OFF_WSUM  + 640;           // 2*9*64*32       [s][k][ci][co]
constexpr int OFF_W2RT  = OFF_W1RT  + 36864;         // 2*32*64         [s][ci][co]
constexpr int OFF_WC2T  = OFF_W2RT  + 4096;          // 64*32           [ci][o]
constexpr int OFF_W1T   = OFF_WC2T  + 2048;          // 9*64*64         [k][ci][co]
constexpr int OFF_T     = OFF_W1T   + 36864;         // 8*64*32*64      [b][i][o][m]
constexpr int OFF_IDX   = OFF_T     + 1048576;       // 512 ints

// ---------------- register-tiled conv GEMM primitives ----------------
// Lane (lr,lc): lr = lane>>3 selects pixel row-octet, lc = lane&7 selects
// co-quad. acc[j][px] = out[co0+lc*4+j][lr*8+px].
// B operand lives in LDS padded im2col layout Bp[ci][10][8] (row 0/9 = zero).
// A operand (weights) read per-lane from global: [.. ci ..][COdim] co-contig.

__device__ __forceinline__ void conv3x3_tile(
    const float* __restrict__ Wg, const int COdim, const int co0,
    const float* __restrict__ Bp, const int ciBase, const int ciN,
    const int lr, const int lc, float acc[4][8])
{
#pragma unroll
  for (int k = 0; k < 9; k++) {
    const int dy = k / 3 - 1, dx = k % 3 - 1;
    const float* wrow = Wg + (k * 64 + ciBase) * COdim + co0 + lc * 4;
    const float* brow = Bp + ciBase * 80 + (1 + lr + dy) * 8;
#pragma unroll 4
    for (int ci = 0; ci < ciN; ci++) {
      float4 wv = *(const float4*)(wrow + ci * COdim);
      float4 b0 = *(const float4*)(brow + ci * 80);
      float4 b1 = *(const float4*)(brow + ci * 80 + 4);
      float bb[8] = {b0.x, b0.y, b0.z, b0.w, b1.x, b1.y, b1.z, b1.w};
      float wj[4] = {wv.x, wv.y, wv.z, wv.w};
#pragma unroll
      for (int j = 0; j < 4; j++)
#pragma unroll
        for (int px = 0; px < 8; px++) {
          const int sx = px + dx;
          if (sx >= 0 && sx <= 7) acc[j][px] = fmaf(wj[j], bb[sx], acc[j][px]);
        }
    }
  }
}

__device__ __forceinline__ void conv1x1_tile(
    const float* __restrict__ Wg, const int COdim, const int co0,
    const float* __restrict__ Bp, const int ciBase, const int ciN,
    const int lr, const int lc, float acc[4][8])
{
  const float* wbase = Wg + ciBase * COdim + co0 + lc * 4;
  const float* bbase = Bp + ciBase * 80 + (1 + lr) * 8;
#pragma unroll 4
  for (int ci = 0; ci < ciN; ci++) {
    float4 wv = *(const float4*)(wbase + ci * COdim);
    float4 b0 = *(const float4*)(bbase + ci * 80);
    float4 b1 = *(const float4*)(bbase + ci * 80 + 4);
    float bb[8] = {b0.x, b0.y, b0.z, b0.w, b1.x, b1.y, b1.z, b1.w};
    float wj[4] = {wv.x, wv.y, wv.z, wv.w};
#pragma unroll
    for (int j = 0; j < 4; j++)
#pragma unroll
      for (int px = 0; px < 8; px++)
        acc[j][px] = fmaf(wj[j], bb[px], acc[j][px]);
  }
}

__device__ __forceinline__ void store_tile(float* dst, int lr, int lc,
                                           const float acc[4][8])
{
#pragma unroll
  for (int j = 0; j < 4; j++) {
    *(float4*)(dst + (lc * 4 + j) * 64 + lr * 8) =
        make_float4(acc[j][0], acc[j][1], acc[j][2], acc[j][3]);
    *(float4*)(dst + (lc * 4 + j) * 64 + lr * 8 + 4) =
        make_float4(acc[j][4], acc[j][5], acc[j][6], acc[j][7]);
  }
}

// Hopfield over one token; pat staged in LDS with +1 padding (row stride 33)
// so per-lane reads hit distinct banks. All 64 lanes cooperate (lane = e&63,
// 8 chunks of 64 patterns each). Returns un-normalized q and 1/denom.
__device__ __forceinline__ void hopfield_token_lds(
    const float* __restrict__ patS, const float* Ys, int tok, int lane,
    float q[32], float& inv_d)
{
  const float* patL = patS + lane * 33;
  float l[8];
#pragma unroll
  for (int k = 0; k < 8; k++) l[k] = 0.f;
  for (int c = 0; c < 32; c++) {
    float yv = Ys[c * 64 + tok];
#pragma unroll
    for (int k = 0; k < 8; k++) l[k] = fmaf(yv, patL[k * 2112 + c], l[k]);
  }
  const float s = 0.17677669529663687f; // 1/sqrt(32)
  float mx = -1e30f;
#pragma unroll
  for (int k = 0; k < 8; k++) { l[k] *= s; mx = fmaxf(mx, l[k]); }
#pragma unroll
  for (int off = 32; off > 0; off >>= 1) mx = fmaxf(mx, __shfl_xor(mx, off, 64));
  float num[8]; float dsum = 0.f;
#pragma unroll
  for (int k = 0; k < 8; k++) { num[k] = __expf(l[k] - mx); dsum += num[k]; }
#pragma unroll
  for (int off = 32; off > 0; off >>= 1) dsum += __shfl_xor(dsum, off, 64);
#pragma unroll
  for (int c = 0; c < 32; c++) q[c] = 0.f;
#pragma unroll
  for (int k = 0; k < 8; k++) {
    float nk = num[k];
    const float* pp = patL + k * 2112;
#pragma unroll
    for (int c = 0; c < 32; c++) q[c] = fmaf(nk, pp[c], q[c]);
  }
#pragma unroll
  for (int off = 32; off > 0; off >>= 1) {
#pragma unroll
    for (int c = 0; c < 32; c++) q[c] += __shfl_xor(q[c], off, 64);
  }
  inv_d = 1.f / dsum;
}

// ---------------- kW: weight transposes ----------------
__global__ __launch_bounds__(1024) void kW(
    const float* __restrict__ w1, const float* __restrict__ r0w1,
    const float* __restrict__ r0w2, const float* __restrict__ r1w1,
    const float* __restrict__ r1w2, const float* __restrict__ w2, float* ws)
{
  const int t0 = blockIdx.x * 1024 + threadIdx.x;
  const int stride = gridDim.x * 1024;
  for (int e = t0; e < 36864; e += stride) {
    int co = e & 63, ci = (e >> 6) & 63, k = e >> 12;
    ws[OFF_W1T + e] = w1[(co * 64 + ci) * 9 + k];
  }
  for (int e = t0; e < 18432; e += stride) {
    int co = e & 31, ci = (e >> 5) & 63, k = e >> 11;
    ws[OFF_W1RT + e]         = r0w1[(co * 64 + ci) * 9 + k];
    ws[OFF_W1RT + 18432 + e] = r1w1[(co * 64 + ci) * 9 + k];
  }
  for (int e = t0; e < 2048; e += stride) {
    int co = e & 63, ci = e >> 6;
    ws[OFF_W2RT + e]        = r0w2[co * 32 + ci];
    ws[OFF_W2RT + 2048 + e] = r1w2[co * 32 + ci];
    int o = e & 31, c2 = e >> 5;
    ws[OFF_WC2T + e] = w2[o * 64 + c2];
  }
  for (int e = t0; e < 576; e += stride) {
    int k = e >> 6, co = e & 63;
    float a = 0.f;
    for (int ci = 0; ci < 64; ci++) a += w1[(co * 64 + ci) * 9 + k];
    ws[OFF_WSUM + e] = a; // [k][co]
  }
}

// ---------------- kX: X1W precompute (8b x 9k blocks) ----------------
__global__ __launch_bounds__(256) void kX(const float* __restrict__ x,
                                          const float* __restrict__ wsc,
                                          float* ws)
{
  const int bk = blockIdx.x, b = bk / 9, k = bk % 9;
  const int t = threadIdx.x, w = t >> 6, lane = t & 63;
  const int lr = lane >> 3, lc = lane & 7;
  __shared__ __align__(16) float Xp[5120];
  __shared__ __align__(16) float Pq[8192];
  for (int e = t; e < 4096; e += 256) {
    int ci = e >> 6, p = e & 63;
    Xp[ci * 80 + 8 + p] = x[b * 4096 + e];  // rows 1..8 = (1+py)*8+px = 8+p
  }
  __syncthreads();
  float acc[4][8];
#pragma unroll
  for (int j = 0; j < 4; j++)
#pragma unroll
    for (int px = 0; px < 8; px++) acc[j][px] = 0.f;
  const int cohalf = w & 1, ks = w >> 1;
  conv1x1_tile(wsc + OFF_W1T + k * 4096, 64, cohalf * 32, Xp, ks * 32, 32, lr, lc, acc);
  store_tile(Pq + ks * 4096 + cohalf * 2048, lr, lc, acc);
  __syncthreads();
  for (int e = t; e < 4096; e += 256) {
    int co = e & 63, i = e >> 6;
    int pin = (co >> 5) * 2048 + (co & 31) * 64 + i;
    ws[OFF_X1W + ((b * 64 + i) * 9 + k) * 64 + co] = Pq[pin] + Pq[4096 + pin];
  }
}

// ---------------- kF: forward + masks + g ----------------
__global__ __launch_bounds__(1024) void kF(
    const float* __restrict__ x, const float* __restrict__ b1,
    const float* __restrict__ b2, const float* __restrict__ pat,
    const float* __restrict__ wsc, float* ws)
{
  const int b = blockIdx.x, t = threadIdx.x;
  const int w = t >> 6, lane = t & 63, lr = lane >> 3, lc = lane & 7;
  __shared__ __align__(16) float Apad[5120];   // padded activations [ci][10][8]
  __shared__ __align__(16) float Yl[4096];     // pre-relu residual state
  __shared__ __align__(16) float Pq[16896];    // K-split partials / pat overlay
  __shared__ __align__(16) float Hpad[2560];   // res branch hidden [32][10][8]
  __shared__ __align__(16) float Ys[2048];     // final y [32][64]

  // build padded x
  for (int e = t; e < 5120; e += 1024) {
    int ci = e / 80, rr = e % 80, r = rr >> 3, c = rr & 7;
    Apad[e] = (r >= 1 && r <= 8) ? x[((b * 64 + ci) * 8 + (r - 1)) * 8 + c] : 0.f;
  }
  __syncthreads();

  float acc[4][8];
  // conv1: 8 waves: cohalf x 4 K-splits (ci 16 each)
  if (w < 8) {
#pragma unroll
    for (int j = 0; j < 4; j++)
#pragma unroll
      for (int px = 0; px < 8; px++) acc[j][px] = 0.f;
    const int cohalf = w & 1, ks = w >> 1;
    conv3x3_tile(wsc + OFF_W1T, 64, cohalf * 32, Apad, ks * 16, 16, lr, lc, acc);
    store_tile(Pq + ks * 4096 + cohalf * 2048, lr, lc, acc);
  }
  __syncthreads();
  // reduce + bias + mask M0 + relu -> Apad
  for (int e = t; e < 4096; e += 1024) {
    int co = e >> 6, p = e & 63;
    int pin = (co >> 5) * 2048 + (co & 31) * 64 + p;
    float s = b1[co];
#pragma unroll
    for (int ks = 0; ks < 4; ks++) s += Pq[ks * 4096 + pin];
    Yl[e] = s;
    ws[OFF_MASKM + (b * 3 + 0) * 4096 + e] = s > 0.f ? 1.f : 0.f;
    Apad[co * 80 + 8 + p] = fmaxf(s, 0.f);
  }
  __syncthreads();

  for (int s = 0; s < 2; s++) {
    // res conv3x3 64->32: 8 waves K-split (ci 8 each)
    if (w < 8) {
#pragma unroll
      for (int j = 0; j < 4; j++)
#pragma unroll
        for (int px = 0; px < 8; px++) acc[j][px] = 0.f;
      conv3x3_tile(wsc + OFF_W1RT + s * 18432, 32, 0, Apad, w * 8, 8, lr, lc, acc);
      store_tile(Pq + w * 2048, lr, lc, acc);
    }
    __syncthreads();
    // reduce, mask N, relu -> Hpad
    for (int e = t; e < 2048; e += 1024) {
      int rh = e >> 6, p = e & 63;
      float hv = 0.f;
#pragma unroll
      for (int ks = 0; ks < 8; ks++) hv += Pq[ks * 2048 + e];
      ws[OFF_MASKN + (b * 2 + s) * 2048 + e] = hv > 0.f ? 1.f : 0.f;
      Hpad[rh * 80 + 8 + p] = fmaxf(hv, 0.f);
    }
    __syncthreads();
    // res 1x1 32->64: 8 waves: cohalf x 4 K-splits (ci 8 each)
    if (w < 8) {
#pragma unroll
      for (int j = 0; j < 4; j++)
#pragma unroll
        for (int px = 0; px < 8; px++) acc[j][px] = 0.f;
      const int cohalf = w & 1, ks = w >> 1;
      conv1x1_tile(wsc + OFF_W2RT + s * 2048, 64, cohalf * 32, Hpad, ks * 8, 8, lr, lc, acc);
      store_tile(Pq + ks * 4096 + cohalf * 2048, lr, lc, acc);
    }
    __syncthreads();
    // reduce + residual + mask M + relu -> Apad
    for (int e = t; e < 4096; e += 1024) {
      int co = e >> 6, p = e & 63;
      int pin = (co >> 5) * 2048 + (co & 31) * 64 + p;
      float d = 0.f;
#pragma unroll
      for (int ks = 0; ks < 4; ks++) d += Pq[ks * 4096 + pin];
      float ny = Yl[e] + d;
      Yl[e] = ny;
      ws[OFF_MASKM + (b * 3 + 1 + s) * 4096 + e] = ny > 0.f ? 1.f : 0.f;
      Apad[co * 80 + 8 + p] = fmaxf(ny, 0.f);
    }
    __syncthreads();
  }

  // conv2 1x1 64->32: 8 waves K-split (ci 8 each)
  if (w < 8) {
#pragma unroll
    for (int j = 0; j < 4; j++)
#pragma unroll
      for (int px = 0; px < 8; px++) acc[j][px] = 0.f;
    conv1x1_tile(wsc + OFF_WC2T, 32, 0, Apad, w * 8, 8, lr, lc, acc);
    store_tile(Pq + w * 2048, lr, lc, acc);
  }
  __syncthreads();
  for (int e = t; e < 2048; e += 1024) {
    int o = e >> 6;
    float yv = b2[o];
#pragma unroll
    for (int ks = 0; ks < 8; ks++) yv += Pq[ks * 2048 + e];
    Ys[e] = yv;
  }
  __syncthreads();
  // stage pat into Pq with +1 padding (stride 33)
  for (int e = t; e < 16384; e += 1024) Pq[(e >> 5) * 33 + (e & 31)] = pat[e];
  __syncthreads();
  // g = 2*(y - yq)
  for (int tok = w; tok < 64; tok += 16) {
    float q[32]; float invd;
    hopfield_token_lds(Pq, Ys, tok, lane, q, invd);
    if (lane == 0) {
#pragma unroll
      for (int c = 0; c < 32; c++)
        ws[OFF_G + b * 2048 + c * 64 + tok] = 2.f * (Ys[c * 64 + tok] - q[c] * invd);
    }
  }
}

// ---------------- kJ: one wave per tangent ----------------
__global__ __launch_bounds__(64) void kJ(const float* __restrict__ wsc, float* ws)
{
  const int bid = blockIdx.x;
  const int type = bid & 1, i = (bid >> 1) & 63, b = bid >> 7;
  const int lane = threadIdx.x;
  const int lr = lane >> 3, lc = lane & 7;
  const int p = lane, py = p >> 3, px = p & 7, iy = i >> 3, ix = i & 7;
  __shared__ __align__(16) float Tc[4096];  // tangent state [ci][p]
  __shared__ __align__(16) float Up[5120];  // padded im2col / Vp / Vf overlay

  // zero pad rows 0 and 9 (never overwritten: all later writes hit rows 1..8)
  for (int e = lane; e < 1024; e += 64) {
    int ci = e >> 4, r9 = (e >> 3) & 1, c = e & 7;
    Up[ci * 80 + r9 * 72 + c] = 0.f;
  }

  // t0 init from X1W / Wsum
  {
    int kh = iy - py + 1, kw = ix - px + 1;
    bool v0 = (unsigned)kh < 3u && (unsigned)kw < 3u;
    int kidx = v0 ? kh * 3 + kw : 0;
    const float* src = type ? (wsc + OFF_X1W + ((b * 64 + i) * 9 + kidx) * 64)
                            : (wsc + OFF_WSUM + kidx * 64);
    const float4* s4 = (const float4*)src;
    for (int c4 = 0; c4 < 16; c4++) {
      float4 tv = s4[c4];
      Tc[(c4 * 4 + 0) * 64 + p] = v0 ? tv.x : 0.f;
      Tc[(c4 * 4 + 1) * 64 + p] = v0 ? tv.y : 0.f;
      Tc[(c4 * 4 + 2) * 64 + p] = v0 ? tv.z : 0.f;
      Tc[(c4 * 4 + 3) * 64 + p] = v0 ? tv.w : 0.f;
    }
  }
  __syncthreads();

  float acc[4][8];
  for (int s = 0; s < 2; s++) {
    // build Upad = M_s * Tc
    const float* Mp = wsc + OFF_MASKM + (b * 3 + s) * 4096;
    for (int ci = 0; ci < 64; ci++)
      Up[ci * 80 + 8 + p] = Tc[ci * 64 + p] * Mp[ci * 64 + p];
    __syncthreads();
    // conv3x3 64->32
#pragma unroll
    for (int j = 0; j < 4; j++)
#pragma unroll
      for (int pq = 0; pq < 8; pq++) acc[j][pq] = 0.f;
    conv3x3_tile(wsc + OFF_W1RT + s * 18432, 32, 0, Up, 0, 64, lr, lc, acc);
    __syncthreads();  // everyone done reading Up before Vp overlay
    // Vp = N * v  (padded layout, rows 1..8)
    const float* Np = wsc + OFF_MASKN + (b * 2 + s) * 2048;
#pragma unroll
    for (int j = 0; j < 4; j++) {
      int rh = lc * 4 + j;
#pragma unroll
      for (int half = 0; half < 2; half++) {
        float4 nv = *(const float4*)(Np + rh * 64 + lr * 8 + half * 4);
        *(float4*)(&Up[rh * 80 + (1 + lr) * 8 + half * 4]) =
            make_float4(acc[j][half * 4 + 0] * nv.x, acc[j][half * 4 + 1] * nv.y,
                        acc[j][half * 4 + 2] * nv.z, acc[j][half * 4 + 3] * nv.w);
      }
    }
    __syncthreads();
    // dT = W2^T Vp (K=32) ; T += dT
#pragma unroll
    for (int h = 0; h < 2; h++) {
      float a2[4][8];
#pragma unroll
      for (int j = 0; j < 4; j++)
#pragma unroll
        for (int pq = 0; pq < 8; pq++) a2[j][pq] = 0.f;
      conv1x1_tile(wsc + OFF_W2RT + s * 2048, 64, h * 32, Up, 0, 32, lr, lc, a2);
#pragma unroll
      for (int j = 0; j < 4; j++) {
        int co = h * 32 + lc * 4 + j;
#pragma unroll
        for (int half = 0; half < 2; half++) {
          float4 tv = *(const float4*)(&Tc[co * 64 + lr * 8 + half * 4]);
          *(float4*)(&Tc[co * 64 + lr * 8 + half * 4]) =
              make_float4(tv.x + a2[j][half * 4 + 0], tv.y + a2[j][half * 4 + 1],
                          tv.z + a2[j][half * 4 + 2], tv.w + a2[j][half * 4 + 3]);
        }
      }
    }
    __syncthreads();
  }

  // final 1x1 with M2 mask
  {
    const float* M2p = wsc + OFF_MASKM + (b * 3 + 2) * 4096;
    for (int ci = 0; ci < 64; ci++)
      Up[ci * 80 + 8 + p] = Tc[ci * 64 + p] * M2p[ci * 64 + p];
    __syncthreads();
#pragma unroll
    for (int j = 0; j < 4; j++)
#pragma unroll
      for (int pq = 0; pq < 8; pq++) acc[j][pq] = 0.f;
    conv1x1_tile(wsc + OFF_WC2T, 32, 0, Up, 0, 64, lr, lc, acc);
  }

  if (type == 0) {
    // e[m] = sum_o g[o][m]*out[o][m]; argmin_m (first index on ties)
    const float* gp = wsc + OFF_G + b * 2048;
    float e8[8];
#pragma unroll
    for (int pq = 0; pq < 8; pq++) e8[pq] = 0.f;
#pragma unroll
    for (int j = 0; j < 4; j++) {
      int o = lc * 4 + j;
      float4 g0 = *(const float4*)(gp + o * 64 + lr * 8);
      float4 g1 = *(const float4*)(gp + o * 64 + lr * 8 + 4);
      e8[0] = fmaf(g0.x, acc[j][0], e8[0]);
      e8[1] = fmaf(g0.y, acc[j][1], e8[1]);
      e8[2] = fmaf(g0.z, acc[j][2], e8[2]);
      e8[3] = fmaf(g0.w, acc[j][3], e8[3]);
      e8[4] = fmaf(g1.x, acc[j][4], e8[4]);
      e8[5] = fmaf(g1.y, acc[j][5], e8[5]);
      e8[6] = fmaf(g1.z, acc[j][6], e8[6]);
      e8[7] = fmaf(g1.w, acc[j][7], e8[7]);
    }
#pragma unroll
    for (int off = 1; off <= 4; off <<= 1)
#pragma unroll
      for (int pq = 0; pq < 8; pq++) e8[pq] += __shfl_xor(e8[pq], off, 64);
    float bv = e8[0]; int bi = lr * 8;
#pragma unroll
    for (int pq = 1; pq < 8; pq++)
      if (e8[pq] < bv) { bv = e8[pq]; bi = lr * 8 + pq; }
#pragma unroll
    for (int off = 8; off <= 32; off <<= 1) {
      float ov = __shfl_xor(bv, off, 64);
      int oi = __shfl_xor(bi, off, 64);
      if (ov < bv || (ov == bv && oi < bi)) { bv = ov; bi = oi; }
    }
    if (lane == 0) ((int*)(ws + OFF_IDX))[b * 64 + i] = bi;
  } else {
    float* Tp = ws + OFF_T + (b * 64 + i) * 2048;
#pragma unroll
    for (int j = 0; j < 4; j++) {
      int o = lc * 4 + j;
      *(float4*)(Tp + o * 64 + lr * 8) =
          make_float4(acc[j][0], acc[j][1], acc[j][2], acc[j][3]);
      *(float4*)(Tp + o * 64 + lr * 8 + 4) =
          make_float4(acc[j][4], acc[j][5], acc[j][6], acc[j][7]);
    }
  }
}

// ---------------- kH: routed gather + hopfield -> out ----------------
__global__ __launch_bounds__(1024) void kH(const float* __restrict__ wsc,
                                           const float* __restrict__ pat,
                                           float* __restrict__ outp)
{
  const int b = blockIdx.x, t = threadIdx.x, lane = t & 63, w = t >> 6;
  __shared__ __align__(16) float patS[16896];
  __shared__ float Ys[2048];
  __shared__ int sidx[64];
  if (t < 64) sidx[t] = ((const int*)(wsc + OFF_IDX))[b * 64 + t];
  for (int e = t; e < 16384; e += 1024) patS[(e >> 5) * 33 + (e & 31)] = pat[e];
  __syncthreads();
  for (int o = w; o < 32; o += 16) {
    float a = 0.f;
    const float* Tp = wsc + OFF_T + b * 131072 + o * 64 + lane;
    for (int i = 0; i < 64; i++) {
      float tv = Tp[i * 2048];
      a += (sidx[i] == lane) ? tv : 0.f;
    }
    Ys[o * 64 + lane] = a;
  }
  __syncthreads();
  for (int tok = w; tok < 64; tok += 16) {
    float q[32]; float invd;
    hopfield_token_lds(patS, Ys, tok, lane, q, invd);
    if (lane == 0) {
#pragma unroll
      for (int c = 0; c < 32; c++)
        outp[b * 2048 + c * 64 + tok] = q[c] * invd;
    }
  }
}

extern "C" void kernel_launch(void* const* d_in, const int* in_sizes, int n_in,
                              void* d_out, int out_size, void* d_ws, size_t ws_size,
                              hipStream_t stream) {
  (void)in_sizes; (void)n_in; (void)out_size; (void)ws_size;
  const float* x    = (const float*)d_in[0];
  const float* w1   = (const float*)d_in[1];
  const float* b1   = (const float*)d_in[2];
  const float* r0w1 = (const float*)d_in[3];
  const float* r0w2 = (const float*)d_in[4];
  const float* r1w1 = (const float*)d_in[5];
  const float* r1w2 = (const float*)d_in[6];
  const float* w2   = (const float*)d_in[7];
  const float* b2   = (const float*)d_in[8];
  const float* pat  = (const float*)d_in[9];
  float* ws  = (float*)d_ws;
  float* out = (float*)d_out;

  kW<<<8, 1024, 0, stream>>>(w1, r0w1, r0w2, r1w1, r1w2, w2, ws);
  kX<<<72, 256, 0, stream>>>(x, ws, ws);
  kF<<<8, 1024, 0, stream>>>(x, b1, b2, pat, ws, ws);
  kJ<<<1024, 64, 0, stream>>>(ws, ws);
  kH<<<8, 1024, 0, stream>>>(ws, pat, out);
}

// Round 3
// 295.937 us; speedup vs baseline: 6.7008x; 2.9413x over previous
//
#include <hip/hip_runtime.h>
#include <math.h>

// B=8, Cin=64, Cout=32, H=W=8 (P=64), RH=32, E=512.
// kW:    weight transposes + Wsum                          (32 x 1024)
// kX:    X1W[b][i][k][co] = sum_ci x[b,ci,i]*W1[co,ci,k]   (72 x 256)
// kF:    forward (conv1 via X1W gather) + packed masks + y (8 x 1024)
// kHop:  wide hopfield, mode 0: g = 2(y-yq), mode 1: out   (512 x 64)
// kJ:    one wave per (b,i,type) JVP; Tc in registers      (1024 x 64)
// kG:    y_masked gather via idx                           (8 x 512)

// ---- ws layout ----
constexpr int OFF_MBIT = 0;                        // ints: 8*3*64 uint2 = 3072 ints
constexpr int OFF_N    = 3072;                     // 8*2*32*64 floats [b][s][rh][p]
constexpr int OFF_G    = OFF_N    + 32768;         // 8*2048 [b][o][m]
constexpr int OFF_Y    = OFF_G    + 16384;         // 8*64*32 [b][tok][c]
constexpr int OFF_YM   = OFF_Y    + 16384;         // 8*64*32 [b][tok][c]
constexpr int OFF_X1W  = OFF_YM   + 16384;         // 8*64*9*64 [b][i][k][co]
constexpr int OFF_WSUM = OFF_X1W  + 294912;        // 576 pad 640 [k][co]
constexpr int OFF_W1RT = OFF_WSUM + 640;           // 2*9*64*32 [s][k][ci][co32]
constexpr int OFF_W2RT = OFF_W1RT + 36864;         // 2*32*64 [s][ci32][co64]
constexpr int OFF_WC2T = OFF_W2RT + 4096;          // 64*32 [ci64][o32]
constexpr int OFF_W1T  = OFF_WC2T + 2048;          // 9*64*64 [k][ci][co64]
constexpr int OFF_T    = OFF_W1T  + 36864;         // 8*64*64*32 [b][i][m][o]
constexpr int OFF_IDX  = OFF_T    + 1048576;       // 512 ints

// ---------------- register-tiled conv GEMM primitives ----------------
// Lane (lr,lc): acc[j][px] = out[co0+lc*4+j][lr*8+px].
// B operand: LDS padded im2col Bp[ci][10][8] (rows 0/9 zero).
// A operand (weights): per-lane global float4 (vmcnt pipe).

__device__ __forceinline__ void conv3x3_tile(
    const float* __restrict__ Wg, const int COdim, const int co0,
    const float* __restrict__ Bp, const int ciBase, const int ciN,
    const int lr, const int lc, float acc[4][8])
{
#pragma unroll
  for (int k = 0; k < 9; k++) {
    const int dy = k / 3 - 1, dx = k % 3 - 1;
    const float* wrow = Wg + (k * 64 + ciBase) * COdim + co0 + lc * 4;
    const float* brow = Bp + ciBase * 80 + (1 + lr + dy) * 8;
#pragma unroll 4
    for (int ci = 0; ci < ciN; ci++) {
      float4 wv = *(const float4*)(wrow + ci * COdim);
      float4 b0 = *(const float4*)(brow + ci * 80);
      float4 b1 = *(const float4*)(brow + ci * 80 + 4);
      float bb[8] = {b0.x, b0.y, b0.z, b0.w, b1.x, b1.y, b1.z, b1.w};
      float wj[4] = {wv.x, wv.y, wv.z, wv.w};
#pragma unroll
      for (int j = 0; j < 4; j++)
#pragma unroll
        for (int px = 0; px < 8; px++) {
          const int sx = px + dx;
          if (sx >= 0 && sx <= 7) acc[j][px] = fmaf(wj[j], bb[sx], acc[j][px]);
        }
    }
  }
}

__device__ __forceinline__ void conv1x1_tile(
    const float* __restrict__ Wg, const int COdim, const int co0,
    const float* __restrict__ Bp, const int ciBase, const int ciN,
    const int lr, const int lc, float acc[4][8])
{
  const float* wbase = Wg + ciBase * COdim + co0 + lc * 4;
  const float* bbase = Bp + ciBase * 80 + (1 + lr) * 8;
#pragma unroll 4
  for (int ci = 0; ci < ciN; ci++) {
    float4 wv = *(const float4*)(wbase + ci * COdim);
    float4 b0 = *(const float4*)(bbase + ci * 80);
    float4 b1 = *(const float4*)(bbase + ci * 80 + 4);
    float bb[8] = {b0.x, b0.y, b0.z, b0.w, b1.x, b1.y, b1.z, b1.w};
    float wj[4] = {wv.x, wv.y, wv.z, wv.w};
#pragma unroll
    for (int j = 0; j < 4; j++)
#pragma unroll
      for (int px = 0; px < 8; px++)
        acc[j][px] = fmaf(wj[j], bb[px], acc[j][px]);
  }
}

// flat (no-halo) B layout Bf[ci][64]
__device__ __forceinline__ void conv1x1_flat(
    const float* __restrict__ Wg, const int COdim, const int co0,
    const float* __restrict__ Bf, const int ciN,
    const int lr, const int lc, float acc[4][8])
{
  const float* wbase = Wg + co0 + lc * 4;
  const float* bbase = Bf + lr * 8;
#pragma unroll 4
  for (int ci = 0; ci < ciN; ci++) {
    float4 wv = *(const float4*)(wbase + ci * COdim);
    float4 b0 = *(const float4*)(bbase + ci * 64);
    float4 b1 = *(const float4*)(bbase + ci * 64 + 4);
    float bb[8] = {b0.x, b0.y, b0.z, b0.w, b1.x, b1.y, b1.z, b1.w};
    float wj[4] = {wv.x, wv.y, wv.z, wv.w};
#pragma unroll
    for (int j = 0; j < 4; j++)
#pragma unroll
      for (int px = 0; px < 8; px++)
        acc[j][px] = fmaf(wj[j], bb[px], acc[j][px]);
  }
}

__device__ __forceinline__ void store_tile(float* dst, int lr, int lc,
                                           const float acc[4][8])
{
#pragma unroll
  for (int j = 0; j < 4; j++) {
    *(float4*)(dst + (lc * 4 + j) * 64 + lr * 8) =
        make_float4(acc[j][0], acc[j][1], acc[j][2], acc[j][3]);
    *(float4*)(dst + (lc * 4 + j) * 64 + lr * 8 + 4) =
        make_float4(acc[j][4], acc[j][5], acc[j][6], acc[j][7]);
  }
}

// ---------------- kW: weight transposes ----------------
__global__ __launch_bounds__(1024) void kW(
    const float* __restrict__ w1, const float* __restrict__ r0w1,
    const float* __restrict__ r0w2, const float* __restrict__ r1w1,
    const float* __restrict__ r1w2, const float* __restrict__ w2, float* ws)
{
  const int t0 = blockIdx.x * 1024 + threadIdx.x;
  const int stride = gridDim.x * 1024;
  for (int e = t0; e < 36864; e += stride) {
    int co = e & 63, ci = (e >> 6) & 63, k = e >> 12;
    ws[OFF_W1T + e] = w1[(co * 64 + ci) * 9 + k];
  }
  for (int e = t0; e < 18432; e += stride) {
    int co = e & 31, ci = (e >> 5) & 63, k = e >> 11;
    ws[OFF_W1RT + e]         = r0w1[(co * 64 + ci) * 9 + k];
    ws[OFF_W1RT + 18432 + e] = r1w1[(co * 64 + ci) * 9 + k];
  }
  for (int e = t0; e < 2048; e += stride) {
    int co = e & 63, ci = e >> 6;
    ws[OFF_W2RT + e]        = r0w2[co * 32 + ci];
    ws[OFF_W2RT + 2048 + e] = r1w2[co * 32 + ci];
    int o = e & 31, c2 = e >> 5;
    ws[OFF_WC2T + e] = w2[o * 64 + c2];
  }
  for (int e = t0; e < 576; e += stride) {
    int k = e >> 6, co = e & 63;
    float a = 0.f;
    for (int ci = 0; ci < 64; ci++) a += w1[(co * 64 + ci) * 9 + k];
    ws[OFF_WSUM + e] = a;
  }
}

// ---------------- kX: X1W precompute ----------------
__global__ __launch_bounds__(256) void kX(const float* __restrict__ x,
                                          const float* __restrict__ wsc,
                                          float* ws)
{
  const int bk = blockIdx.x, b = bk / 9, k = bk % 9;
  const int t = threadIdx.x, w = t >> 6, lane = t & 63;
  const int lr = lane >> 3, lc = lane & 7;
  __shared__ __align__(16) float Xp[5120];
  __shared__ __align__(16) float Pq[8192];
  for (int e = t; e < 4096; e += 256) {
    int ci = e >> 6, p = e & 63;
    Xp[ci * 80 + 8 + p] = x[b * 4096 + e];
  }
  __syncthreads();
  float acc[4][8];
#pragma unroll
  for (int j = 0; j < 4; j++)
#pragma unroll
    for (int px = 0; px < 8; px++) acc[j][px] = 0.f;
  const int cohalf = w & 1, ks = w >> 1;
  conv1x1_tile(wsc + OFF_W1T + k * 4096, 64, cohalf * 32, Xp, ks * 32, 32, lr, lc, acc);
  store_tile(Pq + ks * 4096 + cohalf * 2048, lr, lc, acc);
  __syncthreads();
  for (int e = t; e < 4096; e += 256) {
    int co = e & 63, i = e >> 6;
    int pin = (co >> 5) * 2048 + (co & 31) * 64 + i;
    ws[OFF_X1W + ((b * 64 + i) * 9 + k) * 64 + co] = Pq[pin] + Pq[4096 + pin];
  }
}

// ---------------- kF: forward + packed masks + y ----------------
__global__ __launch_bounds__(1024) void kF(
    const float* __restrict__ b1, const float* __restrict__ b2,
    const float* __restrict__ wsc, float* ws)
{
  const int b = blockIdx.x, t = threadIdx.x;
  const int w = t >> 6, lane = t & 63, lr = lane >> 3, lc = lane & 7;
  __shared__ __align__(16) float Apad[5120];   // [ci][10][8]
  __shared__ __align__(16) float Yl[4096];     // pre-relu residual state [co][p]
  __shared__ __align__(16) float Pq[16384];    // K-split partials
  __shared__ __align__(16) float Hpad[2560];   // [32][10][8]
  unsigned int* wsi = (unsigned int*)ws;

  // zero pads
  if (t < 1024) {
    int ci = t >> 4, r9 = (t >> 3) & 1, c = t & 7;
    Apad[ci * 80 + r9 * 72 + c] = 0.f;
  }
  if (t < 512) {
    int ci = t >> 4, r9 = (t >> 3) & 1, c = t & 7;
    Hpad[ci * 80 + r9 * 72 + c] = 0.f;
  }

  // conv1 via X1W gather: y1[co,p] = b1[co] + sum_k X1W[b][i_k][k][co]
  {
    const int co4 = t & 15, p = t >> 4;
    const int py = p >> 3, px = p & 7;
    float4 a = ((const float4*)b1)[co4];
#pragma unroll
    for (int k = 0; k < 9; k++) {
      int dy = k / 3 - 1, dx = k % 3 - 1;
      int qy = py + dy, qx = px + dx;
      if ((unsigned)qy < 8u && (unsigned)qx < 8u) {
        int ik = qy * 8 + qx;
        float4 v = *(const float4*)(wsc + OFF_X1W + ((b * 64 + ik) * 9 + k) * 64 + co4 * 4);
        a.x += v.x; a.y += v.y; a.z += v.z; a.w += v.w;
      }
    }
    float av[4] = {a.x, a.y, a.z, a.w};
#pragma unroll
    for (int j = 0; j < 4; j++) {
      int co = co4 * 4 + j;
      Yl[co * 64 + p] = av[j];
      Apad[co * 80 + 8 + p] = fmaxf(av[j], 0.f);
    }
  }
  __syncthreads();
  // M0 packed
  if (t < 64) {
    unsigned int lo = 0, hi = 0;
#pragma unroll
    for (int ci = 0; ci < 32; ci++) lo |= (Yl[ci * 64 + t] > 0.f ? 1u : 0u) << ci;
#pragma unroll
    for (int ci = 0; ci < 32; ci++) hi |= (Yl[(32 + ci) * 64 + t] > 0.f ? 1u : 0u) << ci;
    wsi[OFF_MBIT + ((b * 3 + 0) * 64 + t) * 2]     = lo;
    wsi[OFF_MBIT + ((b * 3 + 0) * 64 + t) * 2 + 1] = hi;
  }

  float acc[4][8];
  for (int s = 0; s < 2; s++) {
    if (w < 8) {
#pragma unroll
      for (int j = 0; j < 4; j++)
#pragma unroll
        for (int px = 0; px < 8; px++) acc[j][px] = 0.f;
      conv3x3_tile(wsc + OFF_W1RT + s * 18432, 32, 0, Apad, w * 8, 8, lr, lc, acc);
      store_tile(Pq + w * 2048, lr, lc, acc);
    }
    __syncthreads();
    for (int e = t; e < 2048; e += 1024) {
      int rh = e >> 6, p = e & 63;
      float hv = 0.f;
#pragma unroll
      for (int ks = 0; ks < 8; ks++) hv += Pq[ks * 2048 + e];
      ws[OFF_N + (b * 2 + s) * 2048 + e] = hv > 0.f ? 1.f : 0.f;
      Hpad[rh * 80 + 8 + p] = fmaxf(hv, 0.f);
    }
    __syncthreads();
    if (w < 8) {
#pragma unroll
      for (int j = 0; j < 4; j++)
#pragma unroll
        for (int px = 0; px < 8; px++) acc[j][px] = 0.f;
      const int cohalf = w & 1, ks = w >> 1;
      conv1x1_tile(wsc + OFF_W2RT + s * 2048, 64, cohalf * 32, Hpad, ks * 8, 8, lr, lc, acc);
      store_tile(Pq + ks * 4096 + cohalf * 2048, lr, lc, acc);
    }
    __syncthreads();
    for (int e = t; e < 4096; e += 1024) {
      int co = e >> 6, p = e & 63;
      int pin = (co >> 5) * 2048 + (co & 31) * 64 + p;
      float d = 0.f;
#pragma unroll
      for (int ks = 0; ks < 4; ks++) d += Pq[ks * 4096 + pin];
      float ny = Yl[e] + d;
      Yl[e] = ny;
      Apad[co * 80 + 8 + p] = fmaxf(ny, 0.f);
    }
    __syncthreads();
    if (t < 64) {
      unsigned int lo = 0, hi = 0;
#pragma unroll
      for (int ci = 0; ci < 32; ci++) lo |= (Yl[ci * 64 + t] > 0.f ? 1u : 0u) << ci;
#pragma unroll
      for (int ci = 0; ci < 32; ci++) hi |= (Yl[(32 + ci) * 64 + t] > 0.f ? 1u : 0u) << ci;
      wsi[OFF_MBIT + ((b * 3 + 1 + s) * 64 + t) * 2]     = lo;
      wsi[OFF_MBIT + ((b * 3 + 1 + s) * 64 + t) * 2 + 1] = hi;
    }
  }

  // conv2 1x1 -> y
  if (w < 8) {
#pragma unroll
    for (int j = 0; j < 4; j++)
#pragma unroll
      for (int px = 0; px < 8; px++) acc[j][px] = 0.f;
    conv1x1_tile(wsc + OFF_WC2T, 32, 0, Apad, w * 8, 8, lr, lc, acc);
    store_tile(Pq + w * 2048, lr, lc, acc);
  }
  __syncthreads();
  for (int e = t; e < 2048; e += 1024) {
    int o = e >> 6, p = e & 63;
    float yv = b2[o];
#pragma unroll
    for (int ks = 0; ks < 8; ks++) yv += Pq[ks * 2048 + e];
    ws[OFF_Y + b * 2048 + p * 32 + o] = yv;  // [b][tok][c]
  }
}

// ---------------- kHop: wide hopfield, one wave per (b,tok) ----------------
__global__ __launch_bounds__(64) void kHop(const float* __restrict__ src,
                                           const float* __restrict__ pat,
                                           float* __restrict__ dst, int mode)
{
  const int b = blockIdx.x >> 6, tok = blockIdx.x & 63;
  const int lane = threadIdx.x;
  const float* yp = src + b * 2048 + tok * 32;
  float4 ya[8];
#pragma unroll
  for (int r = 0; r < 8; r++) ya[r] = ((const float4*)yp)[r];

  float l[8];
#pragma unroll
  for (int j = 0; j < 8; j++) {
    const float4* pp = (const float4*)(pat + (j * 64 + lane) * 32);
    float lj = 0.f;
#pragma unroll
    for (int c4 = 0; c4 < 8; c4++) {
      float4 pv = pp[c4];
      lj = fmaf(ya[c4].x, pv.x, lj);
      lj = fmaf(ya[c4].y, pv.y, lj);
      lj = fmaf(ya[c4].z, pv.z, lj);
      lj = fmaf(ya[c4].w, pv.w, lj);
    }
    l[j] = lj * 0.17677669529663687f;  // 1/sqrt(32)
  }
  float mx = -1e30f;
#pragma unroll
  for (int j = 0; j < 8; j++) mx = fmaxf(mx, l[j]);
#pragma unroll
  for (int off = 32; off > 0; off >>= 1) mx = fmaxf(mx, __shfl_xor(mx, off, 64));
  float num[8]; float dsum = 0.f;
#pragma unroll
  for (int j = 0; j < 8; j++) { num[j] = __expf(l[j] - mx); dsum += num[j]; }
#pragma unroll
  for (int off = 32; off > 0; off >>= 1) dsum += __shfl_xor(dsum, off, 64);

  float q[32];
#pragma unroll
  for (int c = 0; c < 32; c++) q[c] = 0.f;
#pragma unroll
  for (int j = 0; j < 8; j++) {
    const float4* pp = (const float4*)(pat + (j * 64 + lane) * 32);
    float nj = num[j];
#pragma unroll
    for (int c4 = 0; c4 < 8; c4++) {
      float4 pv = pp[c4];
      q[c4 * 4 + 0] = fmaf(nj, pv.x, q[c4 * 4 + 0]);
      q[c4 * 4 + 1] = fmaf(nj, pv.y, q[c4 * 4 + 1]);
      q[c4 * 4 + 2] = fmaf(nj, pv.z, q[c4 * 4 + 2]);
      q[c4 * 4 + 3] = fmaf(nj, pv.w, q[c4 * 4 + 3]);
    }
  }
#pragma unroll
  for (int off = 32; off > 0; off >>= 1) {
#pragma unroll
    for (int c = 0; c < 32; c++) q[c] += __shfl_xor(q[c], off, 64);
  }
  if (lane == 0) {
    float invd = 1.f / dsum;
    float yy[32];
#pragma unroll
    for (int c4 = 0; c4 < 8; c4++) {
      yy[c4 * 4 + 0] = ya[c4].x; yy[c4 * 4 + 1] = ya[c4].y;
      yy[c4 * 4 + 2] = ya[c4].z; yy[c4 * 4 + 3] = ya[c4].w;
    }
#pragma unroll
    for (int c = 0; c < 32; c++) {
      float qv = q[c] * invd;
      dst[b * 2048 + c * 64 + tok] = mode ? qv : 2.f * (yy[c] - qv);
    }
  }
}

// ---------------- kJ: one wave per (b,i,type); Tc in registers ----------------
__global__ __launch_bounds__(64) void kJ(const float* __restrict__ wsc, float* ws)
{
  const int bid = blockIdx.x;
  const int type = bid & 1, i = (bid >> 1) & 63, b = bid >> 7;
  const int p = threadIdx.x;
  const int lr = p >> 3, lc = p & 7;
  const int py = p >> 3, px = p & 7, iy = i >> 3, ix = i & 7;
  __shared__ __align__(16) float Up[5120];
  const unsigned int* wsi = (const unsigned int*)wsc;

  float Tc[64];
  {
    int kh = iy - py + 1, kw = ix - px + 1;
    bool v0 = (unsigned)kh < 3u && (unsigned)kw < 3u;
    int kidx = v0 ? kh * 3 + kw : 0;
    const float4* s4 = (const float4*)(type
        ? (wsc + OFF_X1W + ((b * 64 + i) * 9 + kidx) * 64)
        : (wsc + OFF_WSUM + kidx * 64));
#pragma unroll
    for (int c4 = 0; c4 < 16; c4++) {
      float4 tv = s4[c4];
      Tc[c4 * 4 + 0] = v0 ? tv.x : 0.f;
      Tc[c4 * 4 + 1] = v0 ? tv.y : 0.f;
      Tc[c4 * 4 + 2] = v0 ? tv.z : 0.f;
      Tc[c4 * 4 + 3] = v0 ? tv.w : 0.f;
    }
  }

  float accA[4][8], accB[4][8];
  for (int s = 0; s < 2; s++) {
    // re-zero pad rows (clobbered by previous stage's flat overlay)
#pragma unroll
    for (int l = 0; l < 16; l++) {
      int e = l * 64 + p;
      Up[(e >> 4) * 80 + ((e >> 3) & 1) * 72 + (e & 7)] = 0.f;
    }
    // masked U (packed mask: one uint2 per lane)
    uint2 mb = ((const uint2*)(wsi + OFF_MBIT))[(b * 3 + s) * 64 + p];
#pragma unroll
    for (int ci = 0; ci < 64; ci++) {
      bool m = ((ci < 32 ? (mb.x >> ci) : (mb.y >> (ci - 32))) & 1u) != 0u;
      Up[ci * 80 + 8 + p] = m ? Tc[ci] : 0.f;
    }
    __syncthreads();
#pragma unroll
    for (int j = 0; j < 4; j++)
#pragma unroll
      for (int pq = 0; pq < 8; pq++) accA[j][pq] = 0.f;
    conv3x3_tile(wsc + OFF_W1RT + s * 18432, 32, 0, Up, 0, 64, lr, lc, accA);
    __syncthreads();
    // V = N*v into padded rows (ci 0..31)
    const float* Np = wsc + OFF_N + (b * 2 + s) * 2048;
#pragma unroll
    for (int j = 0; j < 4; j++) {
      int rh = lc * 4 + j;
#pragma unroll
      for (int half = 0; half < 2; half++) {
        float4 nv = *(const float4*)(Np + rh * 64 + lr * 8 + half * 4);
        *(float4*)(&Up[rh * 80 + (1 + lr) * 8 + half * 4]) =
            make_float4(accA[j][half * 4 + 0] * nv.x, accA[j][half * 4 + 1] * nv.y,
                        accA[j][half * 4 + 2] * nv.z, accA[j][half * 4 + 3] * nv.w);
      }
    }
    __syncthreads();
    // dT = W2^T V (both co-halves before overwriting Up)
#pragma unroll
    for (int j = 0; j < 4; j++)
#pragma unroll
      for (int pq = 0; pq < 8; pq++) { accA[j][pq] = 0.f; accB[j][pq] = 0.f; }
    conv1x1_tile(wsc + OFF_W2RT + s * 2048, 64, 0,  Up, 0, 32, lr, lc, accA);
    conv1x1_tile(wsc + OFF_W2RT + s * 2048, 64, 32, Up, 0, 32, lr, lc, accB);
    __syncthreads();
    store_tile(Up, lr, lc, accA);            // flat [co][p], co 0..31
    store_tile(Up + 2048, lr, lc, accB);     // co 32..63
    __syncthreads();
#pragma unroll
    for (int co = 0; co < 64; co++) Tc[co] += Up[co * 64 + p];
    __syncthreads();
  }

  // final 1x1 with M2 mask (flat layout, no halo needed)
  {
    uint2 mb = ((const uint2*)(wsi + OFF_MBIT))[(b * 3 + 2) * 64 + p];
#pragma unroll
    for (int ci = 0; ci < 64; ci++) {
      bool m = ((ci < 32 ? (mb.x >> ci) : (mb.y >> (ci - 32))) & 1u) != 0u;
      Up[ci * 64 + p] = m ? Tc[ci] : 0.f;
    }
    __syncthreads();
#pragma unroll
    for (int j = 0; j < 4; j++)
#pragma unroll
      for (int pq = 0; pq < 8; pq++) accA[j][pq] = 0.f;
    conv1x1_flat(wsc + OFF_WC2T, 32, 0, Up, 64, lr, lc, accA);
  }

  if (type == 0) {
    const float* gp = wsc + OFF_G + b * 2048;
    float e8[8];
#pragma unroll
    for (int pq = 0; pq < 8; pq++) e8[pq] = 0.f;
#pragma unroll
    for (int j = 0; j < 4; j++) {
      int o = lc * 4 + j;
      float4 g0 = *(const float4*)(gp + o * 64 + lr * 8);
      float4 g1 = *(const float4*)(gp + o * 64 + lr * 8 + 4);
      e8[0] = fmaf(g0.x, accA[j][0], e8[0]);
      e8[1] = fmaf(g0.y, accA[j][1], e8[1]);
      e8[2] = fmaf(g0.z, accA[j][2], e8[2]);
      e8[3] = fmaf(g0.w, accA[j][3], e8[3]);
      e8[4] = fmaf(g1.x, accA[j][4], e8[4]);
      e8[5] = fmaf(g1.y, accA[j][5], e8[5]);
      e8[6] = fmaf(g1.z, accA[j][6], e8[6]);
      e8[7] = fmaf(g1.w, accA[j][7], e8[7]);
    }
#pragma unroll
    for (int off = 1; off <= 4; off <<= 1)
#pragma unroll
      for (int pq = 0; pq < 8; pq++) e8[pq] += __shfl_xor(e8[pq], off, 64);
    float bv = e8[0]; int bi = lr * 8;
#pragma unroll
    for (int pq = 1; pq < 8; pq++)
      if (e8[pq] < bv) { bv = e8[pq]; bi = lr * 8 + pq; }
#pragma unroll
    for (int off = 8; off <= 32; off <<= 1) {
      float ov = __shfl_xor(bv, off, 64);
      int oi = __shfl_xor(bi, off, 64);
      if (ov < bv || (ov == bv && oi < bi)) { bv = ov; bi = oi; }
    }
    if (p == 0) ((int*)(ws + OFF_IDX))[b * 64 + i] = bi;
  } else {
    float* Tp = ws + OFF_T + (b * 64 + i) * 2048;  // [m][o]
#pragma unroll
    for (int pq = 0; pq < 8; pq++) {
      *(float4*)(Tp + (lr * 8 + pq) * 32 + lc * 4) =
          make_float4(accA[0][pq], accA[1][pq], accA[2][pq], accA[3][pq]);
    }
  }
}

// ---------------- kG: routed gather ----------------
__global__ __launch_bounds__(512) void kG(const float* __restrict__ wsc, float* ws)
{
  const int b = blockIdx.x, t = threadIdx.x;
  __shared__ int sidx[64];
  if (t < 64) sidx[t] = ((const int*)(wsc + OFF_IDX))[b * 64 + t];
  __syncthreads();
  const int c4 = t & 7, tok = t >> 3;
  float4 a = make_float4(0.f, 0.f, 0.f, 0.f);
  const float* Tp = wsc + OFF_T + b * 131072 + tok * 32 + c4 * 4;
#pragma unroll 4
  for (int i = 0; i < 64; i++) {
    float sel = (sidx[i] == tok) ? 1.f : 0.f;
    float4 tv = *(const float4*)(Tp + i * 2048);
    a.x = fmaf(sel, tv.x, a.x);
    a.y = fmaf(sel, tv.y, a.y);
    a.z = fmaf(sel, tv.z, a.z);
    a.w = fmaf(sel, tv.w, a.w);
  }
  *(float4*)(ws + OFF_YM + b * 2048 + tok * 32 + c4 * 4) = a;
}

extern "C" void kernel_launch(void* const* d_in, const int* in_sizes, int n_in,
                              void* d_out, int out_size, void* d_ws, size_t ws_size,
                              hipStream_t stream) {
  (void)in_sizes; (void)n_in; (void)out_size; (void)ws_size;
  const float* x    = (const float*)d_in[0];
  const float* w1   = (const float*)d_in[1];
  const float* b1   = (const float*)d_in[2];
  const float* r0w1 = (const float*)d_in[3];
  const float* r0w2 = (const float*)d_in[4];
  const float* r1w1 = (const float*)d_in[5];
  const float* r1w2 = (const float*)d_in[6];
  const float* w2   = (const float*)d_in[7];
  const float* b2   = (const float*)d_in[8];
  const float* pat  = (const float*)d_in[9];
  float* ws  = (float*)d_ws;
  float* out = (float*)d_out;

  kW<<<32, 1024, 0, stream>>>(w1, r0w1, r0w2, r1w1, r1w2, w2, ws);
  kX<<<72, 256, 0, stream>>>(x, ws, ws);
  kF<<<8, 1024, 0, stream>>>(b1, b2, ws, ws);
  kHop<<<512, 64, 0, stream>>>(ws + OFF_Y, pat, ws + OFF_G, 0);
  kJ<<<1024, 64, 0, stream>>>(ws, ws);
  kG<<<8, 512, 0, stream>>>(ws, ws);
  kHop<<<512, 64, 0, stream>>>(ws + OFF_YM, pat, out, 1);
}